// Round 15
// baseline (384.600 us; speedup 1.0000x reference)
//
#include <hip/hip_runtime.h>

// MultiHeadAttention: B=8, S=256, D=4096, H=16, HD=256 (fp32 in/out)
// R15: R14 with gemm256 moved to the m201 phase rhythm:
//   - staging spread 1 chunk/phase (c1@ph0, c2@ph1, c3@ph2, c0(t+2)@ph3)
//   - DOUBLE barrier per phase (post-MFMA barrier added -> wave role-split)
//   - vmcnt(2)/tile + ph3 lgkmcnt(0) handshake unchanged (ledger identical)
// Everything else (cvt_all, gemm_dp V/O, attention) byte-identical to R14.

typedef _Float16 f16;
typedef f16 f16x8 __attribute__((ext_vector_type(8)));
typedef float f32x4 __attribute__((ext_vector_type(4)));

__device__ __forceinline__ void g2lds(const f16* g, f16* l) {
  __builtin_amdgcn_global_load_lds((const __attribute__((address_space(1))) void*)g,
                                   (__attribute__((address_space(3))) void*)l, 16, 0, 0);
}

// One dispatch converts q,k,v (4096 blocks each) + Wq,Wk,Wv,Wo (8192 each).
// Slab boundaries: 4096/8192/12288 (q,k,v), 20480/28672/36864/45056 (weights).
__global__ __launch_bounds__(256) void cvt_all(
    const float* __restrict__ s0, const float* __restrict__ s1,
    const float* __restrict__ s2, const float* __restrict__ s3,
    const float* __restrict__ s4, const float* __restrict__ s5,
    const float* __restrict__ s6,
    f16* __restrict__ d0, f16* __restrict__ d1, f16* __restrict__ d2,
    f16* __restrict__ d3, f16* __restrict__ d4, f16* __restrict__ d5,
    f16* __restrict__ d6)
{
  int b = blockIdx.x;
  const float* src; f16* dst;
  if (b < 4096)        { src = s0; dst = d0; }
  else if (b < 8192)   { src = s1; dst = d1; b -= 4096; }
  else if (b < 12288)  { src = s2; dst = d2; b -= 8192; }
  else if (b < 20480)  { src = s3; dst = d3; b -= 12288; }
  else if (b < 28672)  { src = s4; dst = d4; b -= 20480; }
  else if (b < 36864)  { src = s5; dst = d5; b -= 28672; }
  else                 { src = s6; dst = d6; b -= 36864; }
  const int i = (b * 256 + threadIdx.x) * 8;
  float4 a = *(const float4*)(src + i);
  float4 c = *(const float4*)(src + i + 4);
  f16x8 o;
  o[0] = (f16)a.x; o[1] = (f16)a.y; o[2] = (f16)a.z; o[3] = (f16)a.w;
  o[4] = (f16)c.x; o[5] = (f16)c.y; o[6] = (f16)c.z; o[7] = (f16)c.w;
  *(f16x8*)(dst + i) = o;
}

#define MFMA8x(ACC, FA, FB, MO, NO)                                             \
  do {                                                                          \
    __builtin_amdgcn_s_setprio(1);                                              \
    _Pragma("unroll")                                                           \
    for (int m_ = 0; m_ < (MO); ++m_)                                           \
      _Pragma("unroll")                                                         \
      for (int n_ = 0; n_ < (NO); ++n_)                                         \
        _Pragma("unroll")                                                       \
        for (int ks_ = 0; ks_ < 2; ++ks_)                                       \
          ACC = __builtin_amdgcn_mfma_f32_16x16x32_f16(FA[m_][ks_], FB[n_][ks_],\
                                                       ACC, 0, 0, 0);           \
    __builtin_amdgcn_s_setprio(0);                                              \
  } while (0)

// ---------------------------------------------------------------------------
// Q+K fused: 256x256 tile, K=4096, BK=64, 8 waves (2Mx4N) of 128x64.
// LDS 2 dbuf x 4 chunks x 128x64 f16 = 128 KB, XOR-swizzled.
// m201 rhythm: per phase {stage 1 chunk; ds_read next frags; BAR;
// setprio-MFMA; BAR}. vmcnt(2) once per tile at ph3 + lgkmcnt(0) handshake.
// ---------------------------------------------------------------------------
__global__ __launch_bounds__(512, 2) void gemm256(
    const f16* __restrict__ Aq, const f16* __restrict__ Ak,
    const f16* __restrict__ Bq, const f16* __restrict__ Bk,
    const float* __restrict__ bq, const float* __restrict__ bk,
    const int* __restrict__ mask,
    f16* __restrict__ Qbh, f16* __restrict__ Kbh)
{
  __shared__ __align__(16) f16 lds[2][4][8192];
  const int tid = threadIdx.x;
  const int lane = tid & 63, wid = tid >> 6;
  const int wm = wid >> 2, wn = wid & 3;
  const int ln = lane & 15, lh = lane >> 4;
  const int lnx = ln & 7;
  const int K = 4096, NT = 64;

  const int seg = blockIdx.x >> 7;
  int inner = blockIdx.x & 127;
  inner = (inner & 7) * 16 + (inner >> 3);        // XCD swizzle (bijective)

  const f16* A   = (seg == 0) ? Aq : Ak;
  const f16* B   = (seg == 0) ? Bq : Bk;
  const float* bias = (seg == 0) ? bq : bk;
  const int bm = inner % 8, bn = inner / 8;

  const size_t Abase = (size_t)bm * 256 * K;
  const size_t Bbase = (size_t)bn * 256 * K;
  const int sr = tid >> 3;
  const int ss = (tid & 7) ^ (sr & 7);

#define STAGEC(tt, bb_, c)                                                       \
  do {                                                                           \
    const f16* base_ = ((c) < 2) ? A + Abase + (size_t)((c) * 128) * K           \
                                 : B + Bbase + (size_t)(((c) - 2) * 128) * K;    \
    f16* dst_ = &lds[bb_][c][0];                                                 \
    g2lds(base_ + (size_t)sr * K + ((tt) << 6) + ss * 8, dst_ + tid * 8);        \
    g2lds(base_ + (size_t)(64 + sr) * K + ((tt) << 6) + ss * 8,                  \
          dst_ + (512 + tid) * 8);                                               \
  } while (0)

#define RD_A03(buf) do { _Pragma("unroll")                                       \
  for (int m_ = 0; m_ < 4; ++m_) _Pragma("unroll")                               \
    for (int k_ = 0; k_ < 2; ++k_)                                               \
      a03[m_][k_] = *(const f16x8*)&(buf)[(m_ * 16 + ln) * 64 + ((k_ * 4 + lh) ^ lnx) * 8]; } while (0)
#define RD_A47(buf) do { _Pragma("unroll")                                       \
  for (int m_ = 0; m_ < 4; ++m_) _Pragma("unroll")                               \
    for (int k_ = 0; k_ < 2; ++k_)                                               \
      a47[m_][k_] = *(const f16x8*)&(buf)[((64 + m_ * 16) + ln) * 64 + ((k_ * 4 + lh) ^ lnx) * 8]; } while (0)
#define RD_B01(buf) do { _Pragma("unroll")                                       \
  for (int n_ = 0; n_ < 2; ++n_) _Pragma("unroll")                               \
    for (int k_ = 0; k_ < 2; ++k_)                                               \
      b01[n_][k_] = *(const f16x8*)&(buf)[(brow + n_ * 16 + ln) * 64 + ((k_ * 4 + lh) ^ lnx) * 8]; } while (0)
#define RD_B23(buf) do { _Pragma("unroll")                                       \
  for (int n_ = 0; n_ < 2; ++n_) _Pragma("unroll")                               \
    for (int k_ = 0; k_ < 2; ++k_)                                               \
      b23[n_][k_] = *(const f16x8*)&(buf)[(brow + 32 + n_ * 16 + ln) * 64 + ((k_ * 4 + lh) ^ lnx) * 8]; } while (0)

  f32x4 acc[8][4] = {};
  f16x8 a03[4][2], a47[4][2], b01[2][2], b23[2][2];
  const int brow = (wn & 1) * 64;

  STAGEC(0, 0, 0); STAGEC(0, 0, 1); STAGEC(0, 0, 2); STAGEC(0, 0, 3);
  STAGEC(1, 1, 0);
  asm volatile("s_waitcnt vmcnt(2)" ::: "memory");
  __builtin_amdgcn_s_barrier();
  {
    const f16* cA0 = &lds[0][wm][0];
    const f16* cB0 = &lds[0][2 + (wn >> 1)][0];
    RD_A03(cA0); RD_B01(cB0);
  }

  for (int t = 0; t < NT; ++t) {
    const int bb = t & 1;
    const f16* cA = &lds[bb][wm][0];
    const f16* cB = &lds[bb][2 + (wn >> 1)][0];
    const f16* cAn = &lds[bb ^ 1][wm][0];
    const f16* cBn = &lds[bb ^ 1][2 + (wn >> 1)][0];

    // ph0: stage c1(t+1); read b23(t); BAR; MFMA q0; BAR
    if (t + 1 < NT) STAGEC(t + 1, bb ^ 1, 1);
    RD_B23(cB);
    __builtin_amdgcn_s_barrier();
    MFMA8x(acc[m_][n_], a03, b01, 4, 2);
    __builtin_amdgcn_s_barrier();

    // ph1: stage c2(t+1); read a47(t); BAR; MFMA q1; BAR
    if (t + 1 < NT) STAGEC(t + 1, bb ^ 1, 2);
    RD_A47(cA);
    __builtin_amdgcn_s_barrier();
    MFMA8x(acc[m_][2 + n_], a03, b23, 4, 2);
    __builtin_amdgcn_s_barrier();

    // ph2: stage c3(t+1); BAR; MFMA q2; BAR
    if (t + 1 < NT) STAGEC(t + 1, bb ^ 1, 3);
    __builtin_amdgcn_s_barrier();
    MFMA8x(acc[4 + m_][n_], a47, b01, 4, 2);
    __builtin_amdgcn_s_barrier();

    // ph3: stage c0(t+2); vmcnt(2); lgkm drain; BAR; read next a03/b01; q3; BAR
    if (t + 2 < NT) {
      STAGEC(t + 2, bb, 0);
      asm volatile("s_waitcnt vmcnt(2)" ::: "memory");
    } else {
      asm volatile("s_waitcnt vmcnt(0)" ::: "memory");
    }
    asm volatile("s_waitcnt lgkmcnt(0)" ::: "memory");
    __builtin_amdgcn_s_barrier();
    if (t + 1 < NT) { RD_A03(cAn); RD_B01(cBn); }
    MFMA8x(acc[4 + m_][2 + n_], a47, b23, 4, 2);
    __builtin_amdgcn_s_barrier();
  }
#undef STAGEC
#undef RD_A03
#undef RD_A47
#undef RD_B01
#undef RD_B23

#pragma unroll
  for (int mf = 0; mf < 8; ++mf)
#pragma unroll
    for (int nf = 0; nf < 4; ++nf)
#pragma unroll
      for (int i = 0; i < 4; ++i) {
        int R = bm * 256 + wm * 128 + mf * 16 + lh * 4 + i;
        int C = bn * 256 + wn * 64 + nf * 16 + ln;
        float v = acc[mf][nf][i];
        v += bias[C];
        v = mask[(R >> 8) * 256 + (C & 255)] ? v : 0.0f;
        f16* o = (seg == 0) ? Qbh : Kbh;
        o[(size_t)((R >> 8) * 16 + (C >> 8)) * 65536 +
          (size_t)(R & 255) * 256 + (C & 255)] = (f16)v;
      }
}

// C = A @ B^T. Tile 128x256, BK=64, 8 waves (2Mx4N of 64x64), 3-buffer LDS
// ring, counted vmcnt(6), reg-frag dbuf. [R3/R7-proven]
// EPI 1: V proj (A=Wv, B=v) -> f16 Vt [b,h,d,s] + bias[R]
// EPI 2: O proj -> fp32 [M][N] + bias
template<int EPI>
__global__ __launch_bounds__(512, 2) void gemm_dp(
    const f16* __restrict__ A, const f16* __restrict__ B,
    const float* __restrict__ bias, void* __restrict__ out,
    int M, int N, int K)
{
  __shared__ __align__(16) f16 lds[3 * 24576];
  const int tid = threadIdx.x;
  const int lane = tid & 63, wid = tid >> 6;
  const int wm = wid >> 2, wn = wid & 3;
  const int ln = lane & 15, lh = lane >> 4;
  const int bm = blockIdx.y, bn = blockIdx.x;

  const size_t Abase = (size_t)bm * 128 * K;
  const size_t Bbase = (size_t)bn * 256 * K;
  const int sr = tid >> 3;
  const int ss = (tid & 7) ^ (sr & 7);
  const int NT = K >> 6;

  f16* p0 = &lds[0];
  f16* p1 = &lds[24576];
  f16* p2 = &lds[2 * 24576];

#define STAGE(t_, bo_, part)                                                    \
  do {                                                                          \
    const int kt_ = (t_) << 6;                                                  \
    if ((part) == 0) {                                                          \
      g2lds(A + Abase + (size_t)sr * K + kt_ + ss * 8,         (bo_) + tid * 8);  \
      g2lds(B + Bbase + (size_t)sr * K + kt_ + ss * 8,         (bo_) + 8192 + tid * 8); \
      g2lds(B + Bbase + (size_t)(64 + sr) * K + kt_ + ss * 8,  (bo_) + 8192 + (512 + tid) * 8); \
    } else {                                                                    \
      g2lds(A + Abase + (size_t)(64 + sr) * K + kt_ + ss * 8,  (bo_) + (512 + tid) * 8); \
      g2lds(B + Bbase + (size_t)(128 + sr) * K + kt_ + ss * 8, (bo_) + 8192 + (1024 + tid) * 8); \
      g2lds(B + Bbase + (size_t)(192 + sr) * K + kt_ + ss * 8, (bo_) + 8192 + (1536 + tid) * 8); \
    }                                                                           \
  } while (0)

  const int lx = ln & 7;
  const int arow = (wm * 64 + ln) * 64;
  const int brow = (wn * 64 + ln) * 64;

#define LOADFRAGS(fa, fb, buf, ks)                                              \
  do {                                                                          \
    const f16* bA_ = (buf);                                                     \
    const f16* bB_ = (buf) + 8192;                                              \
    const int so_ = (((ks) * 4 + lh) ^ lx) * 8;                                 \
    _Pragma("unroll")                                                           \
    for (int mf = 0; mf < 4; ++mf)                                              \
      fa[mf] = *(const f16x8*)&bA_[arow + mf * 1024 + so_];                     \
    _Pragma("unroll")                                                           \
    for (int nf = 0; nf < 4; ++nf)                                              \
      fb[nf] = *(const f16x8*)&bB_[brow + nf * 1024 + so_];                     \
  } while (0)

#define MFMA16(fa, fb)                                                          \
  do {                                                                          \
    __builtin_amdgcn_s_setprio(1);                                              \
    _Pragma("unroll")                                                           \
    for (int mf = 0; mf < 4; ++mf)                                              \
      _Pragma("unroll")                                                         \
      for (int nf = 0; nf < 4; ++nf)                                            \
        acc[mf][nf] = __builtin_amdgcn_mfma_f32_16x16x32_f16(fa[mf], fb[nf],    \
                                                             acc[mf][nf], 0, 0, 0); \
    __builtin_amdgcn_s_setprio(0);                                              \
  } while (0)

  f32x4 acc[4][4] = {};
  f16x8 ca[4], cb[4], na[4], nb[4];

  STAGE(0, p0, 0); STAGE(0, p0, 1);
  STAGE(1, p1, 0); STAGE(1, p1, 1);
  asm volatile("s_waitcnt vmcnt(6)" ::: "memory");
  __builtin_amdgcn_s_barrier();
  asm volatile("" ::: "memory");
  LOADFRAGS(ca, cb, p0, 0);

  for (int t = 0; t < NT; ++t) {
    LOADFRAGS(na, nb, p0, 1);
    if (t + 2 < NT) { STAGE(t + 2, p2, 0); STAGE(t + 2, p2, 1); }
    MFMA16(ca, cb);

    if (t + 1 < NT) {
      if (t + 2 < NT) {
        asm volatile("s_waitcnt vmcnt(6)" ::: "memory");
      } else {
        asm volatile("s_waitcnt vmcnt(0)" ::: "memory");
      }
      __builtin_amdgcn_s_barrier();
      asm volatile("" ::: "memory");
      LOADFRAGS(ca, cb, p1, 0);
      MFMA16(na, nb);
      asm volatile("" ::: "memory");
      __builtin_amdgcn_s_barrier();
      asm volatile("" ::: "memory");
      f16* tp = p0; p0 = p1; p1 = p2; p2 = tp;
    } else {
      MFMA16(na, nb);
    }
  }
#undef STAGE
#undef LOADFRAGS
#undef MFMA16

#pragma unroll
  for (int mf = 0; mf < 4; ++mf)
#pragma unroll
    for (int nf = 0; nf < 4; ++nf)
#pragma unroll
      for (int i = 0; i < 4; ++i) {
        int R = bm * 128 + wm * 64 + mf * 16 + lh * 4 + i;
        int C = bn * 256 + wn * 64 + nf * 16 + ln;
        float v = acc[mf][nf][i];
        if (EPI == 1) {
          v += bias[R];
          ((f16*)out)[(size_t)(C >> 8) * 1048576 + (size_t)R * 256 + (C & 255)] = (f16)v;
        } else {
          v += bias[C];
          ((float*)out)[(size_t)R * N + C] = v;
        }
      }
}

// One block per (bh, 64-row q-block). Q:[bh][s][d], K:[bh][s][d] (masked),
// Vt:[bh][d][s]. aout: f16 [b*256+s][h*256+d] scaled by 1/64.
__global__ __launch_bounds__(256) void attn_kernel(
    const f16* __restrict__ Q, const f16* __restrict__ Kt,
    const f16* __restrict__ Vt, f16* __restrict__ aout)
{
  __shared__ __align__(16) f16 tile[64 * 256];
  __shared__ __align__(16) f16 pbuf[64 * 256];
  const int tid = threadIdx.x;
  const int lane = tid & 63, w = tid >> 6;
  const int ln = lane & 15, lh = lane >> 4;
  const int bh = blockIdx.x >> 2, rb = blockIdx.x & 3;
  const int b = bh >> 4, h = bh & 15;
  const size_t hb = (size_t)bh * 65536;

  const int strow = tid >> 5;
  const int stsl  = (tid & 31) ^ (strow & 7);

  f16x8 aq[8];
  {
    const f16* qp = Q + hb + (size_t)(rb * 64 + w * 16 + ln) * 256;
#pragma unroll
    for (int ks = 0; ks < 8; ++ks)
      aq[ks] = *(const f16x8*)(qp + ks * 32 + lh * 8);
  }

  f32x4 sacc[16] = {};

  for (int kt = 0; kt < 4; ++kt) {
#pragma unroll
    for (int c = 0; c < 8; ++c) {
      int L = c * 256 + tid;
      int row = c * 8 + strow;
      g2lds(Kt + hb + (size_t)(kt * 64 + row) * 256 + stsl * 8, &tile[L * 8]);
    }
    __syncthreads();
#pragma unroll
    for (int nf = 0; nf < 4; ++nf) {
      f16x8 bf[8];
#pragma unroll
      for (int ks = 0; ks < 8; ++ks) {
        int r = nf * 16 + ln;
        int sl = (ks * 4 + lh) ^ (r & 7);
        bf[ks] = *(const f16x8*)&tile[r * 256 + sl * 8];
      }
#pragma unroll
      for (int ks = 0; ks < 8; ++ks)
        sacc[kt * 4 + nf] = __builtin_amdgcn_mfma_f32_16x16x32_f16(
            aq[ks], bf[ks], sacc[kt * 4 + nf], 0, 0, 0);
    }
    __syncthreads();
  }

  const float SC = 1.0f / 16.0f;
  float mrow[4] = {-1e30f, -1e30f, -1e30f, -1e30f};
#pragma unroll
  for (int t = 0; t < 16; ++t)
#pragma unroll
    for (int i = 0; i < 4; ++i) mrow[i] = fmaxf(mrow[i], sacc[t][i]);
#pragma unroll
  for (int i = 0; i < 4; ++i) {
    mrow[i] = fmaxf(mrow[i], __shfl_xor(mrow[i], 1));
    mrow[i] = fmaxf(mrow[i], __shfl_xor(mrow[i], 2));
    mrow[i] = fmaxf(mrow[i], __shfl_xor(mrow[i], 4));
    mrow[i] = fmaxf(mrow[i], __shfl_xor(mrow[i], 8));
  }
  float ssum[4] = {0.f, 0.f, 0.f, 0.f};
#pragma unroll
  for (int t = 0; t < 16; ++t)
#pragma unroll
    for (int i = 0; i < 4; ++i) {
      float p = __expf((sacc[t][i] - mrow[i]) * SC);
      sacc[t][i] = p;
      ssum[i] += p;
    }
#pragma unroll
  for (int i = 0; i < 4; ++i) {
    ssum[i] += __shfl_xor(ssum[i], 1);
    ssum[i] += __shfl_xor(ssum[i], 2);
    ssum[i] += __shfl_xor(ssum[i], 4);
    ssum[i] += __shfl_xor(ssum[i], 8);
  }
  float rs[4];
#pragma unroll
  for (int i = 0; i < 4; ++i) rs[i] = 1.0f / ssum[i];

#pragma unroll
  for (int t = 0; t < 16; ++t)
#pragma unroll
    for (int i = 0; i < 4; ++i) {
      int row = w * 16 + lh * 4 + i;
      int col = (t >> 2) * 64 + (t & 3) * 16 + ln;
      pbuf[row * 256 + (col ^ ((row & 7) << 3))] = (f16)(sacc[t][i] * rs[i]);
    }

  f16x8 pa[8];
  {
    int r = w * 16 + ln;
#pragma unroll
    for (int ks = 0; ks < 8; ++ks) {
      int col = ks * 32 + lh * 8;
      pa[ks] = *(const f16x8*)&pbuf[r * 256 + (col ^ ((r & 7) << 3))];
    }
  }

  for (int dt = 0; dt < 4; ++dt) {
#pragma unroll
    for (int c = 0; c < 8; ++c) {
      int L = c * 256 + tid;
      int row = c * 8 + strow;
      g2lds(Vt + hb + (size_t)(dt * 64 + row) * 256 + stsl * 8, &tile[L * 8]);
    }
    __syncthreads();
    f32x4 oacc[4] = {};
#pragma unroll
    for (int nf = 0; nf < 4; ++nf) {
      f16x8 bf[8];
#pragma unroll
      for (int ks = 0; ks < 8; ++ks) {
        int r = nf * 16 + ln;
        int sl = (ks * 4 + lh) ^ (r & 7);
        bf[ks] = *(const f16x8*)&tile[r * 256 + sl * 8];
      }
#pragma unroll
      for (int ks = 0; ks < 8; ++ks)
        oacc[nf] = __builtin_amdgcn_mfma_f32_16x16x32_f16(pa[ks], bf[ks], oacc[nf], 0, 0, 0);
    }
#pragma unroll
    for (int nf = 0; nf < 4; ++nf)
#pragma unroll
      for (int i = 0; i < 4; ++i) {
        int s = rb * 64 + w * 16 + lh * 4 + i;
        int d = dt * 64 + nf * 16 + ln;
        aout[(size_t)(b * 256 + s) * 4096 + h * 256 + d] = (f16)(oacc[nf][i] * 0.015625f);
      }
    __syncthreads();
  }
}

extern "C" void kernel_launch(void* const* d_in, const int* in_sizes, int n_in,
                              void* d_out, int out_size, void* d_ws, size_t ws_size,
                              hipStream_t stream) {
  const float* q  = (const float*)d_in[0];
  const float* k  = (const float*)d_in[1];
  const float* v  = (const float*)d_in[2];
  const int*   mk = (const int*)d_in[3];
  const float* Wq = (const float*)d_in[4];
  const float* bq = (const float*)d_in[5];
  const float* Wk = (const float*)d_in[6];
  const float* bk = (const float*)d_in[7];
  const float* Wv = (const float*)d_in[8];
  const float* bv = (const float*)d_in[9];
  const float* Wo = (const float*)d_in[10];
  const float* bo = (const float*)d_in[11];
  float* out = (float*)d_out;

  const size_t NQ = 2048ull * 4096;
  const size_t NW = 4096ull * 4096;
  f16* ws = (f16*)d_ws;
  f16* q16  = ws;
  f16* k16  = q16 + NQ;
  f16* v16  = k16 + NQ;
  f16* Wq16 = v16 + NQ;
  f16* Wk16 = Wq16 + NW;
  f16* Wv16 = Wk16 + NW;
  f16* Wo16 = Wv16 + NW;
  f16* Qbh  = Wo16 + NW;
  f16* Kbh  = Qbh + NQ;
  f16* Vt   = Kbh + NQ;
  f16* at16 = Vt + NQ;

  // single merged convert dispatch: 3x4096 + 4x8192 = 45056 blocks
  cvt_all<<<45056, 256, 0, stream>>>(q, k, v, Wq, Wk, Wv, Wo,
                                     q16, k16, v16, Wq16, Wk16, Wv16, Wo16);

  // Q+K projections: 256 blocks, m201-rhythm schedule
  gemm256<<<256, 512, 0, stream>>>(q16, k16, Wq16, Wk16, bq, bk, mk, Qbh, Kbh);
  // V projection: A=Wv (M=4096), B=v16 (N=2048): 256 blocks (8x32)
  gemm_dp<1><<<dim3(8, 32), 512, 0, stream>>>(Wv16, v16, bv, Vt, 4096, 2048, 4096);
  // attention
  attn_kernel<<<512, 256, 0, stream>>>(Qbh, Kbh, Vt, at16);
  // O projection: 256 blocks (16x16)
  gemm_dp<2><<<dim3(16, 16), 512, 0, stream>>>(at16, Wo16, bo, out, 2048, 4096, 4096);
}

// Round 16
// 367.997 us; speedup vs baseline: 1.0451x; 1.0451x over previous
//
#include <hip/hip_runtime.h>

// MultiHeadAttention: B=8, S=256, D=4096, H=16, HD=256 (fp32 in/out)
// R16 (FINAL): revert to R14, the best verified configuration (369.4 us;
// R15's m201-rhythm probe regressed gemm256 126->147 us and is dropped).
//  - cvt_all:  7 tensors, 45056 blocks, single dispatch (~90 us, HBM-bound)
//  - Q+K proj: gemm256 read-ahead 4-phase, 256 blocks   [R9: 126 us, 1090 TF]
//  - V proj:   gemm_dp<1> 3-buffer ring, 256 blocks     [R3/R7: 82 us]
//  - attention: 1-dispatch fused QK^T/softmax/PV        [~25 us]
//  - O proj:   gemm_dp<2>                               [R3/R7: 82 us]

typedef _Float16 f16;
typedef f16 f16x8 __attribute__((ext_vector_type(8)));
typedef float f32x4 __attribute__((ext_vector_type(4)));

__device__ __forceinline__ void g2lds(const f16* g, f16* l) {
  __builtin_amdgcn_global_load_lds((const __attribute__((address_space(1))) void*)g,
                                   (__attribute__((address_space(3))) void*)l, 16, 0, 0);
}

// One dispatch converts q,k,v (4096 blocks each) + Wq,Wk,Wv,Wo (8192 each).
// Slab boundaries: 4096/8192/12288 (q,k,v), 20480/28672/36864/45056 (weights).
__global__ __launch_bounds__(256) void cvt_all(
    const float* __restrict__ s0, const float* __restrict__ s1,
    const float* __restrict__ s2, const float* __restrict__ s3,
    const float* __restrict__ s4, const float* __restrict__ s5,
    const float* __restrict__ s6,
    f16* __restrict__ d0, f16* __restrict__ d1, f16* __restrict__ d2,
    f16* __restrict__ d3, f16* __restrict__ d4, f16* __restrict__ d5,
    f16* __restrict__ d6)
{
  int b = blockIdx.x;
  const float* src; f16* dst;
  if (b < 4096)        { src = s0; dst = d0; }
  else if (b < 8192)   { src = s1; dst = d1; b -= 4096; }
  else if (b < 12288)  { src = s2; dst = d2; b -= 8192; }
  else if (b < 20480)  { src = s3; dst = d3; b -= 12288; }
  else if (b < 28672)  { src = s4; dst = d4; b -= 20480; }
  else if (b < 36864)  { src = s5; dst = d5; b -= 28672; }
  else                 { src = s6; dst = d6; b -= 36864; }
  const int i = (b * 256 + threadIdx.x) * 8;
  float4 a = *(const float4*)(src + i);
  float4 c = *(const float4*)(src + i + 4);
  f16x8 o;
  o[0] = (f16)a.x; o[1] = (f16)a.y; o[2] = (f16)a.z; o[3] = (f16)a.w;
  o[4] = (f16)c.x; o[5] = (f16)c.y; o[6] = (f16)c.z; o[7] = (f16)c.w;
  *(f16x8*)(dst + i) = o;
}

#define MFMA8x(ACC, FA, FB, MO, NO)                                             \
  do {                                                                          \
    __builtin_amdgcn_s_setprio(1);                                              \
    _Pragma("unroll")                                                           \
    for (int m_ = 0; m_ < (MO); ++m_)                                           \
      _Pragma("unroll")                                                         \
      for (int n_ = 0; n_ < (NO); ++n_)                                         \
        _Pragma("unroll")                                                       \
        for (int ks_ = 0; ks_ < 2; ++ks_)                                       \
          ACC = __builtin_amdgcn_mfma_f32_16x16x32_f16(FA[m_][ks_], FB[n_][ks_],\
                                                       ACC, 0, 0, 0);           \
    __builtin_amdgcn_s_setprio(0);                                              \
  } while (0)

// ---------------------------------------------------------------------------
// Q+K fused: 256x256 tile, K=4096, BK=64, 8 waves (2Mx4N) of 128x64.
// LDS 2 dbuf x 4 chunks x 128x64 f16 = 128 KB, XOR-swizzled. Read-ahead
// 4-phase schedule, vmcnt(2)/tile. [R9-exact]
// ---------------------------------------------------------------------------
__global__ __launch_bounds__(512, 2) void gemm256(
    const f16* __restrict__ Aq, const f16* __restrict__ Ak,
    const f16* __restrict__ Bq, const f16* __restrict__ Bk,
    const float* __restrict__ bq, const float* __restrict__ bk,
    const int* __restrict__ mask,
    f16* __restrict__ Qbh, f16* __restrict__ Kbh)
{
  __shared__ __align__(16) f16 lds[2][4][8192];
  const int tid = threadIdx.x;
  const int lane = tid & 63, wid = tid >> 6;
  const int wm = wid >> 2, wn = wid & 3;
  const int ln = lane & 15, lh = lane >> 4;
  const int lnx = ln & 7;
  const int K = 4096, NT = 64;

  const int seg = blockIdx.x >> 7;
  int inner = blockIdx.x & 127;
  inner = (inner & 7) * 16 + (inner >> 3);        // XCD swizzle (bijective)

  const f16* A   = (seg == 0) ? Aq : Ak;
  const f16* B   = (seg == 0) ? Bq : Bk;
  const float* bias = (seg == 0) ? bq : bk;
  const int bm = inner % 8, bn = inner / 8;

  const size_t Abase = (size_t)bm * 256 * K;
  const size_t Bbase = (size_t)bn * 256 * K;
  const int sr = tid >> 3;
  const int ss = (tid & 7) ^ (sr & 7);

#define STAGEC(tt, bb_, c)                                                       \
  do {                                                                           \
    const f16* base_ = ((c) < 2) ? A + Abase + (size_t)((c) * 128) * K           \
                                 : B + Bbase + (size_t)(((c) - 2) * 128) * K;    \
    f16* dst_ = &lds[bb_][c][0];                                                 \
    g2lds(base_ + (size_t)sr * K + ((tt) << 6) + ss * 8, dst_ + tid * 8);        \
    g2lds(base_ + (size_t)(64 + sr) * K + ((tt) << 6) + ss * 8,                  \
          dst_ + (512 + tid) * 8);                                               \
  } while (0)

#define RD_A03(buf) do { _Pragma("unroll")                                       \
  for (int m_ = 0; m_ < 4; ++m_) _Pragma("unroll")                               \
    for (int k_ = 0; k_ < 2; ++k_)                                               \
      a03[m_][k_] = *(const f16x8*)&(buf)[(m_ * 16 + ln) * 64 + ((k_ * 4 + lh) ^ lnx) * 8]; } while (0)
#define RD_A47(buf) do { _Pragma("unroll")                                       \
  for (int m_ = 0; m_ < 4; ++m_) _Pragma("unroll")                               \
    for (int k_ = 0; k_ < 2; ++k_)                                               \
      a47[m_][k_] = *(const f16x8*)&(buf)[((64 + m_ * 16) + ln) * 64 + ((k_ * 4 + lh) ^ lnx) * 8]; } while (0)
#define RD_B01(buf) do { _Pragma("unroll")                                       \
  for (int n_ = 0; n_ < 2; ++n_) _Pragma("unroll")                               \
    for (int k_ = 0; k_ < 2; ++k_)                                               \
      b01[n_][k_] = *(const f16x8*)&(buf)[(brow + n_ * 16 + ln) * 64 + ((k_ * 4 + lh) ^ lnx) * 8]; } while (0)
#define RD_B23(buf) do { _Pragma("unroll")                                       \
  for (int n_ = 0; n_ < 2; ++n_) _Pragma("unroll")                               \
    for (int k_ = 0; k_ < 2; ++k_)                                               \
      b23[n_][k_] = *(const f16x8*)&(buf)[(brow + 32 + n_ * 16 + ln) * 64 + ((k_ * 4 + lh) ^ lnx) * 8]; } while (0)

  f32x4 acc[8][4] = {};
  f16x8 a03[4][2], a47[4][2], b01[2][2], b23[2][2];
  const int brow = (wn & 1) * 64;

  STAGEC(0, 0, 0); STAGEC(0, 0, 1); STAGEC(0, 0, 2); STAGEC(0, 0, 3);
  STAGEC(1, 1, 0);
  asm volatile("s_waitcnt vmcnt(2)" ::: "memory");
  __builtin_amdgcn_s_barrier();
  {
    const f16* cA0 = &lds[0][wm][0];
    const f16* cB0 = &lds[0][2 + (wn >> 1)][0];
    RD_A03(cA0); RD_B01(cB0);
  }

  for (int t = 0; t < NT; ++t) {
    const int bb = t & 1;
    const f16* cA = &lds[bb][wm][0];
    const f16* cB = &lds[bb][2 + (wn >> 1)][0];
    const f16* cAn = &lds[bb ^ 1][wm][0];
    const f16* cBn = &lds[bb ^ 1][2 + (wn >> 1)][0];

    // ph0: stage t+1 bulk; read b23 (for q1); MFMA q0 (counted lgkm)
    if (t + 1 < NT) { STAGEC(t + 1, bb ^ 1, 1); STAGEC(t + 1, bb ^ 1, 2); STAGEC(t + 1, bb ^ 1, 3); }
    RD_B23(cB);
    __builtin_amdgcn_s_barrier();
    MFMA8x(acc[m_][n_], a03, b01, 4, 2);

    // ph1: read a47 (for q2); MFMA q1
    RD_A47(cA);
    __builtin_amdgcn_s_barrier();
    MFMA8x(acc[m_][2 + n_], a03, b23, 4, 2);

    // ph2: MFMA q2
    __builtin_amdgcn_s_barrier();
    MFMA8x(acc[4 + m_][n_], a47, b01, 4, 2);

    // ph3: stage c0(t+2); vmcnt(2); drain lgkm; bar; read next a03/b01; q3
    if (t + 2 < NT) {
      STAGEC(t + 2, bb, 0);
      asm volatile("s_waitcnt vmcnt(2)" ::: "memory");
    } else {
      asm volatile("s_waitcnt vmcnt(0)" ::: "memory");
    }
    asm volatile("s_waitcnt lgkmcnt(0)" ::: "memory");
    __builtin_amdgcn_s_barrier();
    if (t + 1 < NT) { RD_A03(cAn); RD_B01(cBn); }
    MFMA8x(acc[4 + m_][2 + n_], a47, b23, 4, 2);
  }
#undef STAGEC
#undef RD_A03
#undef RD_A47
#undef RD_B01
#undef RD_B23

#pragma unroll
  for (int mf = 0; mf < 8; ++mf)
#pragma unroll
    for (int nf = 0; nf < 4; ++nf)
#pragma unroll
      for (int i = 0; i < 4; ++i) {
        int R = bm * 256 + wm * 128 + mf * 16 + lh * 4 + i;
        int C = bn * 256 + wn * 64 + nf * 16 + ln;
        float v = acc[mf][nf][i];
        v += bias[C];
        v = mask[(R >> 8) * 256 + (C & 255)] ? v : 0.0f;
        f16* o = (seg == 0) ? Qbh : Kbh;
        o[(size_t)((R >> 8) * 16 + (C >> 8)) * 65536 +
          (size_t)(R & 255) * 256 + (C & 255)] = (f16)v;
      }
}

// C = A @ B^T. Tile 128x256, BK=64, 8 waves (2Mx4N of 64x64), 3-buffer LDS
// ring, counted vmcnt(6), reg-frag dbuf. [R3/R7-proven]
// EPI 1: V proj (A=Wv, B=v) -> f16 Vt [b,h,d,s] + bias[R]
// EPI 2: O proj -> fp32 [M][N] + bias
template<int EPI>
__global__ __launch_bounds__(512, 2) void gemm_dp(
    const f16* __restrict__ A, const f16* __restrict__ B,
    const float* __restrict__ bias, void* __restrict__ out,
    int M, int N, int K)
{
  __shared__ __align__(16) f16 lds[3 * 24576];
  const int tid = threadIdx.x;
  const int lane = tid & 63, wid = tid >> 6;
  const int wm = wid >> 2, wn = wid & 3;
  const int ln = lane & 15, lh = lane >> 4;
  const int bm = blockIdx.y, bn = blockIdx.x;

  const size_t Abase = (size_t)bm * 128 * K;
  const size_t Bbase = (size_t)bn * 256 * K;
  const int sr = tid >> 3;
  const int ss = (tid & 7) ^ (sr & 7);
  const int NT = K >> 6;

  f16* p0 = &lds[0];
  f16* p1 = &lds[24576];
  f16* p2 = &lds[2 * 24576];

#define STAGE(t_, bo_, part)                                                    \
  do {                                                                          \
    const int kt_ = (t_) << 6;                                                  \
    if ((part) == 0) {                                                          \
      g2lds(A + Abase + (size_t)sr * K + kt_ + ss * 8,         (bo_) + tid * 8);  \
      g2lds(B + Bbase + (size_t)sr * K + kt_ + ss * 8,         (bo_) + 8192 + tid * 8); \
      g2lds(B + Bbase + (size_t)(64 + sr) * K + kt_ + ss * 8,  (bo_) + 8192 + (512 + tid) * 8); \
    } else {                                                                    \
      g2lds(A + Abase + (size_t)(64 + sr) * K + kt_ + ss * 8,  (bo_) + (512 + tid) * 8); \
      g2lds(B + Bbase + (size_t)(128 + sr) * K + kt_ + ss * 8, (bo_) + 8192 + (1024 + tid) * 8); \
      g2lds(B + Bbase + (size_t)(192 + sr) * K + kt_ + ss * 8, (bo_) + 8192 + (1536 + tid) * 8); \
    }                                                                           \
  } while (0)

  const int lx = ln & 7;
  const int arow = (wm * 64 + ln) * 64;
  const int brow = (wn * 64 + ln) * 64;

#define LOADFRAGS(fa, fb, buf, ks)                                              \
  do {                                                                          \
    const f16* bA_ = (buf);                                                     \
    const f16* bB_ = (buf) + 8192;                                              \
    const int so_ = (((ks) * 4 + lh) ^ lx) * 8;                                 \
    _Pragma("unroll")                                                           \
    for (int mf = 0; mf < 4; ++mf)                                              \
      fa[mf] = *(const f16x8*)&bA_[arow + mf * 1024 + so_];                     \
    _Pragma("unroll")                                                           \
    for (int nf = 0; nf < 4; ++nf)                                              \
      fb[nf] = *(const f16x8*)&bB_[brow + nf * 1024 + so_];                     \
  } while (0)

#define MFMA16(fa, fb)                                                          \
  do {                                                                          \
    __builtin_amdgcn_s_setprio(1);                                              \
    _Pragma("unroll")                                                           \
    for (int mf = 0; mf < 4; ++mf)                                              \
      _Pragma("unroll")                                                         \
      for (int nf = 0; nf < 4; ++nf)                                            \
        acc[mf][nf] = __builtin_amdgcn_mfma_f32_16x16x32_f16(fa[mf], fb[nf],    \
                                                             acc[mf][nf], 0, 0, 0); \
    __builtin_amdgcn_s_setprio(0);                                              \
  } while (0)

  f32x4 acc[4][4] = {};
  f16x8 ca[4], cb[4], na[4], nb[4];

  STAGE(0, p0, 0); STAGE(0, p0, 1);
  STAGE(1, p1, 0); STAGE(1, p1, 1);
  asm volatile("s_waitcnt vmcnt(6)" ::: "memory");
  __builtin_amdgcn_s_barrier();
  asm volatile("" ::: "memory");
  LOADFRAGS(ca, cb, p0, 0);

  for (int t = 0; t < NT; ++t) {
    LOADFRAGS(na, nb, p0, 1);
    if (t + 2 < NT) { STAGE(t + 2, p2, 0); STAGE(t + 2, p2, 1); }
    MFMA16(ca, cb);

    if (t + 1 < NT) {
      if (t + 2 < NT) {
        asm volatile("s_waitcnt vmcnt(6)" ::: "memory");
      } else {
        asm volatile("s_waitcnt vmcnt(0)" ::: "memory");
      }
      __builtin_amdgcn_s_barrier();
      asm volatile("" ::: "memory");
      LOADFRAGS(ca, cb, p1, 0);
      MFMA16(na, nb);
      asm volatile("" ::: "memory");
      __builtin_amdgcn_s_barrier();
      asm volatile("" ::: "memory");
      f16* tp = p0; p0 = p1; p1 = p2; p2 = tp;
    } else {
      MFMA16(na, nb);
    }
  }
#undef STAGE
#undef LOADFRAGS
#undef MFMA16

#pragma unroll
  for (int mf = 0; mf < 4; ++mf)
#pragma unroll
    for (int nf = 0; nf < 4; ++nf)
#pragma unroll
      for (int i = 0; i < 4; ++i) {
        int R = bm * 128 + wm * 64 + mf * 16 + lh * 4 + i;
        int C = bn * 256 + wn * 64 + nf * 16 + ln;
        float v = acc[mf][nf][i];
        if (EPI == 1) {
          v += bias[R];
          ((f16*)out)[(size_t)(C >> 8) * 1048576 + (size_t)R * 256 + (C & 255)] = (f16)v;
        } else {
          v += bias[C];
          ((float*)out)[(size_t)R * N + C] = v;
        }
      }
}

// One block per (bh, 64-row q-block). Q:[bh][s][d], K:[bh][s][d] (masked),
// Vt:[bh][d][s]. aout: f16 [b*256+s][h*256+d] scaled by 1/64.
__global__ __launch_bounds__(256) void attn_kernel(
    const f16* __restrict__ Q, const f16* __restrict__ Kt,
    const f16* __restrict__ Vt, f16* __restrict__ aout)
{
  __shared__ __align__(16) f16 tile[64 * 256];
  __shared__ __align__(16) f16 pbuf[64 * 256];
  const int tid = threadIdx.x;
  const int lane = tid & 63, w = tid >> 6;
  const int ln = lane & 15, lh = lane >> 4;
  const int bh = blockIdx.x >> 2, rb = blockIdx.x & 3;
  const int b = bh >> 4, h = bh & 15;
  const size_t hb = (size_t)bh * 65536;

  const int strow = tid >> 5;
  const int stsl  = (tid & 31) ^ (strow & 7);

  f16x8 aq[8];
  {
    const f16* qp = Q + hb + (size_t)(rb * 64 + w * 16 + ln) * 256;
#pragma unroll
    for (int ks = 0; ks < 8; ++ks)
      aq[ks] = *(const f16x8*)(qp + ks * 32 + lh * 8);
  }

  f32x4 sacc[16] = {};

  for (int kt = 0; kt < 4; ++kt) {
#pragma unroll
    for (int c = 0; c < 8; ++c) {
      int L = c * 256 + tid;
      int row = c * 8 + strow;
      g2lds(Kt + hb + (size_t)(kt * 64 + row) * 256 + stsl * 8, &tile[L * 8]);
    }
    __syncthreads();
#pragma unroll
    for (int nf = 0; nf < 4; ++nf) {
      f16x8 bf[8];
#pragma unroll
      for (int ks = 0; ks < 8; ++ks) {
        int r = nf * 16 + ln;
        int sl = (ks * 4 + lh) ^ (r & 7);
        bf[ks] = *(const f16x8*)&tile[r * 256 + sl * 8];
      }
#pragma unroll
      for (int ks = 0; ks < 8; ++ks)
        sacc[kt * 4 + nf] = __builtin_amdgcn_mfma_f32_16x16x32_f16(
            aq[ks], bf[ks], sacc[kt * 4 + nf], 0, 0, 0);
    }
    __syncthreads();
  }

  const float SC = 1.0f / 16.0f;
  float mrow[4] = {-1e30f, -1e30f, -1e30f, -1e30f};
#pragma unroll
  for (int t = 0; t < 16; ++t)
#pragma unroll
    for (int i = 0; i < 4; ++i) mrow[i] = fmaxf(mrow[i], sacc[t][i]);
#pragma unroll
  for (int i = 0; i < 4; ++i) {
    mrow[i] = fmaxf(mrow[i], __shfl_xor(mrow[i], 1));
    mrow[i] = fmaxf(mrow[i], __shfl_xor(mrow[i], 2));
    mrow[i] = fmaxf(mrow[i], __shfl_xor(mrow[i], 4));
    mrow[i] = fmaxf(mrow[i], __shfl_xor(mrow[i], 8));
  }
  float ssum[4] = {0.f, 0.f, 0.f, 0.f};
#pragma unroll
  for (int t = 0; t < 16; ++t)
#pragma unroll
    for (int i = 0; i < 4; ++i) {
      float p = __expf((sacc[t][i] - mrow[i]) * SC);
      sacc[t][i] = p;
      ssum[i] += p;
    }
#pragma unroll
  for (int i = 0; i < 4; ++i) {
    ssum[i] += __shfl_xor(ssum[i], 1);
    ssum[i] += __shfl_xor(ssum[i], 2);
    ssum[i] += __shfl_xor(ssum[i], 4);
    ssum[i] += __shfl_xor(ssum[i], 8);
  }
  float rs[4];
#pragma unroll
  for (int i = 0; i < 4; ++i) rs[i] = 1.0f / ssum[i];

#pragma unroll
  for (int t = 0; t < 16; ++t)
#pragma unroll
    for (int i = 0; i < 4; ++i) {
      int row = w * 16 + lh * 4 + i;
      int col = (t >> 2) * 64 + (t & 3) * 16 + ln;
      pbuf[row * 256 + (col ^ ((row & 7) << 3))] = (f16)(sacc[t][i] * rs[i]);
    }

  f16x8 pa[8];
  {
    int r = w * 16 + ln;
#pragma unroll
    for (int ks = 0; ks < 8; ++ks) {
      int col = ks * 32 + lh * 8;
      pa[ks] = *(const f16x8*)&pbuf[r * 256 + (col ^ ((r & 7) << 3))];
    }
  }

  for (int dt = 0; dt < 4; ++dt) {
#pragma unroll
    for (int c = 0; c < 8; ++c) {
      int L = c * 256 + tid;
      int row = c * 8 + strow;
      g2lds(Vt + hb + (size_t)(dt * 64 + row) * 256 + stsl * 8, &tile[L * 8]);
    }
    __syncthreads();
    f32x4 oacc[4] = {};
#pragma unroll
    for (int nf = 0; nf < 4; ++nf) {
      f16x8 bf[8];
#pragma unroll
      for (int ks = 0; ks < 8; ++ks) {
        int r = nf * 16 + ln;
        int sl = (ks * 4 + lh) ^ (r & 7);
        bf[ks] = *(const f16x8*)&tile[r * 256 + sl * 8];
      }
#pragma unroll
      for (int ks = 0; ks < 8; ++ks)
        oacc[nf] = __builtin_amdgcn_mfma_f32_16x16x32_f16(pa[ks], bf[ks], oacc[nf], 0, 0, 0);
    }
#pragma unroll
    for (int nf = 0; nf < 4; ++nf)
#pragma unroll
      for (int i = 0; i < 4; ++i) {
        int s = rb * 64 + w * 16 + lh * 4 + i;
        int d = dt * 64 + nf * 16 + ln;
        aout[(size_t)(b * 256 + s) * 4096 + h * 256 + d] = (f16)(oacc[nf][i] * 0.015625f);
      }
    __syncthreads();
  }
}

extern "C" void kernel_launch(void* const* d_in, const int* in_sizes, int n_in,
                              void* d_out, int out_size, void* d_ws, size_t ws_size,
                              hipStream_t stream) {
  const float* q  = (const float*)d_in[0];
  const float* k  = (const float*)d_in[1];
  const float* v  = (const float*)d_in[2];
  const int*   mk = (const int*)d_in[3];
  const float* Wq = (const float*)d_in[4];
  const float* bq = (const float*)d_in[5];
  const float* Wk = (const float*)d_in[6];
  const float* bk = (const float*)d_in[7];
  const float* Wv = (const float*)d_in[8];
  const float* bv = (const float*)d_in[9];
  const float* Wo = (const float*)d_in[10];
  const float* bo = (const float*)d_in[11];
  float* out = (float*)d_out;

  const size_t NQ = 2048ull * 4096;
  const size_t NW = 4096ull * 4096;
  f16* ws = (f16*)d_ws;
  f16* q16  = ws;
  f16* k16  = q16 + NQ;
  f16* v16  = k16 + NQ;
  f16* Wq16 = v16 + NQ;
  f16* Wk16 = Wq16 + NW;
  f16* Wv16 = Wk16 + NW;
  f16* Wo16 = Wv16 + NW;
  f16* Qbh  = Wo16 + NW;
  f16* Kbh  = Qbh + NQ;
  f16* Vt   = Kbh + NQ;
  f16* at16 = Vt + NQ;

  // single merged convert dispatch: 3x4096 + 4x8192 = 45056 blocks
  cvt_all<<<45056, 256, 0, stream>>>(q, k, v, Wq, Wk, Wv, Wo,
                                     q16, k16, v16, Wq16, Wk16, Wv16, Wo16);

  // Q+K projections: 256 blocks, R9 read-ahead schedule
  gemm256<<<256, 512, 0, stream>>>(q16, k16, Wq16, Wk16, bq, bk, mk, Qbh, Kbh);
  // V projection: A=Wv (M=4096), B=v16 (N=2048): 256 blocks (8x32)
  gemm_dp<1><<<dim3(8, 32), 512, 0, stream>>>(Wv16, v16, bv, Vt, 4096, 2048, 4096);
  // attention
  attn_kernel<<<512, 256, 0, stream>>>(Qbh, Kbh, Vt, at16);
  // O projection: 256 blocks (16x16)
  gemm_dp<2><<<dim3(16, 16), 512, 0, stream>>>(at16, Wo16, bo, out, 2048, 4096, 4096);
}